// Round 3
// baseline (378.646 us; speedup 1.0000x reference)
//
#include <hip/hip_runtime.h>
#include <hip/hip_bf16.h>

typedef __attribute__((ext_vector_type(8))) short short8;
typedef __attribute__((ext_vector_type(4))) float f32x4;

#define NTOP 1000
#define KC   256
#define MROWS 40000

static __device__ __forceinline__ unsigned short f2bf(float x) {
    union { float f; unsigned u; } v; v.f = x;
    unsigned r = (v.u + 0x7FFFu + ((v.u >> 16) & 1u)) >> 16;
    return (unsigned short)r;
}

// Kernel 1: colsum[j] += sum over an 8-row slab of nw. colsum pre-zeroed by memset.
__global__ void k_prep(const float* __restrict__ nw,
                       float* __restrict__ colsum) {
    int j  = blockIdx.x * 256 + threadIdx.x;
    int i0 = blockIdx.y * 8;
    if (j < NTOP) {
        float s = 0.f;
        int iend = min(i0 + 8, NTOP);
        for (int i = i0; i < iend; ++i) s += nw[(size_t)i * NTOP + j];
        atomicAdd(colsum + j, s);
    }
}

// Kernel 2: build B' in MFMA-fragment order:
//   B'[((nt*8 + s)*64 + lane)] (short8) = V_j[n = nt*16 + (lane&15),
//                                             k = s*32 + (lane>>4)*8 + j]
__global__ void k_vj(const float* __restrict__ V,
                     const float* __restrict__ noise,
                     const float* __restrict__ colsum,
                     unsigned short* __restrict__ Bp) {
    int t  = blockIdx.x * 256 + threadIdx.x;   // 0 .. 64*8*64-1 = 32767
    int nt = t >> 9;
    int s  = (t >> 6) & 7;
    int l  = t & 63;
    int lm = l & 15, lq = l >> 4;
    int n  = nt * 16 + lm;
    int k0 = s * 32 + lq * 8;
    union { short8 v; unsigned short us[8]; } pk;
    if (n < NTOP) {
        float cs = colsum[n];
        #pragma unroll
        for (int j = 0; j < 8; ++j) {
            int idx = n * KC + k0 + j;
            pk.us[j] = f2bf(V[idx] * cs + 0.1f * noise[idx]);
        }
    } else {
        #pragma unroll
        for (int j = 0; j < 8; ++j) pk.us[j] = 0;
    }
    reinterpret_cast<short8*>(Bp)[t] = pk.v;
}

// Kernel 3: fused U_emb + GEMM(A@B'^T) + sigmoid + masked Normal log-prob + reduce.
// A-fragments built ONCE per block cooperatively into LDS (8 KB), each wave then
// streams them back per K-step. VGPR stays low -> 8 waves/EU for latency hiding.
__global__ __launch_bounds__(256, 8) void k_main(
    const float* __restrict__ U, const float* __restrict__ w5,
    const float* __restrict__ b1, const short8* __restrict__ Bf,
    const float* __restrict__ R, const int* __restrict__ C,
    float* __restrict__ out)
{
    __shared__ short8 Alds[512];   // 8 s-steps x 64 lanes, 8 KB

    const int tid  = threadIdx.x;
    const int wave = tid >> 6;
    const int l    = tid & 63;
    const int lm = l & 15;       // C/D n within tile
    const int lq = l >> 4;       // quad
    const int m0 = blockIdx.x << 4;

    const float w0 = w5[0], w1 = w5[1], w2 = w5[2], w3 = w5[3], w4 = w5[4];
    const float bb = b1[0];

    // ---- Cooperative A-fragment build: 512 chunks, 2 per thread ----
    // Alds[(s*64 + ll)] (short8) = U_emb[m0 + (ll&15), s*32 + (ll>>4)*8 + j] in bf16
    #pragma unroll
    for (int o = tid; o < 512; o += 256) {
        const int ll = o & 63;
        const int s  = o >> 6;
        const int m  = m0 + (ll & 15);
        const int k0 = (s << 5) + ((ll >> 4) << 3);
        const f32x4* up4 = reinterpret_cast<const f32x4*>(
            U + ((size_t)m * KC + k0) * 5);
        float u[40];
        #pragma unroll
        for (int i = 0; i < 10; ++i) {
            f32x4 t = __builtin_nontemporal_load(up4 + i);
            u[i*4+0] = t.x; u[i*4+1] = t.y; u[i*4+2] = t.z; u[i*4+3] = t.w;
        }
        union { short8 v; unsigned short us[8]; } pk;
        #pragma unroll
        for (int j = 0; j < 8; ++j) {
            float e = u[j*5+0]*w0 + u[j*5+1]*w1 + u[j*5+2]*w2
                    + u[j*5+3]*w3 + u[j*5+4]*w4 + bb;
            pk.us[j] = f2bf(e);
        }
        Alds[o] = pk.v;
    }
    __syncthreads();

    float lpsum = 0.f;

    for (int ns = wave * 4; ns < wave * 4 + 4; ++ns) {
        const int n0 = ns << 6;
        f32x4 acc[4];
        #pragma unroll
        for (int t = 0; t < 4; ++t) acc[t] = (f32x4){0.f, 0.f, 0.f, 0.f};

        #pragma unroll
        for (int s = 0; s < 8; ++s) {
            const short8 afr = Alds[(s << 6) + l];
            #pragma unroll
            for (int t = 0; t < 4; ++t) {
                const short8 bfr = Bf[(((ns * 4 + t) * 8 + s) << 6) + l];
                acc[t] = __builtin_amdgcn_mfma_f32_16x16x32_bf16(afr, bfr, acc[t], 0, 0, 0);
            }
        }

        // Epilogue: C/D layout n = lane&15, m = (lane>>4)*4 + reg
        #pragma unroll
        for (int t = 0; t < 4; ++t) {
            const int n = n0 + t * 16 + lm;
            if (n < NTOP) {
                const size_t base = (size_t)(m0 + (lq << 2)) * NTOP + n;
                float rv[4]; int cv[4];
                #pragma unroll
                for (int r = 0; r < 4; ++r) {
                    rv[r] = __builtin_nontemporal_load(R + base + (size_t)r * NTOP);
                    cv[r] = __builtin_nontemporal_load(C + base + (size_t)r * NTOP);
                }
                #pragma unroll
                for (int r = 0; r < 4; ++r) {
                    float x   = acc[t][r];
                    float muv = 1.f / (1.f + __expf(-x));
                    float d   = rv[r] - muv;
                    float lp  = -50.f * d * d + 1.3836465597893728f;
                    if (cv[r] == 1) lpsum += lp;
                }
            }
        }
    }

    #pragma unroll
    for (int off = 32; off > 0; off >>= 1) lpsum += __shfl_down(lpsum, off);
    if (l == 0) atomicAdd(out, lpsum);
}

extern "C" void kernel_launch(void* const* d_in, const int* in_sizes, int n_in,
                              void* d_out, int out_size, void* d_ws, size_t ws_size,
                              hipStream_t stream) {
    const float* V     = (const float*)d_in[1];
    const float* R     = (const float*)d_in[2];
    const float* nw    = (const float*)d_in[3];
    const float* U     = (const float*)d_in[4];
    const float* w5    = (const float*)d_in[5];
    const float* b1    = (const float*)d_in[6];
    const float* noise = (const float*)d_in[7];
    const int*   C     = (const int*)d_in[8];
    float* out = (float*)d_out;

    // Workspace (known-safe 532,480 B footprint):
    //   colsum: [0, 4000)      (padded to 8192)
    //   Bp    : [8192, 532480) 1024*256*2 = 524288 B
    float*          colsum = (float*)d_ws;
    unsigned short* Bp     = (unsigned short*)((char*)d_ws + 8192);

    hipMemsetAsync(colsum, 0, NTOP * sizeof(float), stream);
    hipMemsetAsync(out, 0, sizeof(float), stream);
    hipLaunchKernelGGL(k_prep, dim3(4, 125), dim3(256), 0, stream, nw, colsum);
    hipLaunchKernelGGL(k_vj, dim3(128), dim3(256), 0, stream,
                       V, noise, colsum, Bp);
    hipLaunchKernelGGL(k_main, dim3(MROWS / 16), dim3(256), 0, stream,
                       U, w5, b1, (const short8*)Bp, R, C, out);
}

// Round 4
// 327.746 us; speedup vs baseline: 1.1553x; 1.1553x over previous
//
#include <hip/hip_runtime.h>
#include <hip/hip_bf16.h>

typedef __attribute__((ext_vector_type(8))) short short8;
typedef __attribute__((ext_vector_type(4))) float f32x4;

#define NTOP 1000
#define KC   256
#define MROWS 40000

static __device__ __forceinline__ unsigned short f2bf(float x) {
    union { float f; unsigned u; } v; v.f = x;
    unsigned r = (v.u + 0x7FFFu + ((v.u >> 16) & 1u)) >> 16;
    return (unsigned short)r;
}

// Kernel 1: colsum[j] += sum over an 8-row slab of nw. colsum pre-zeroed by memset.
__global__ void k_prep(const float* __restrict__ nw,
                       float* __restrict__ colsum) {
    int j  = blockIdx.x * 256 + threadIdx.x;
    int i0 = blockIdx.y * 8;
    if (j < NTOP) {
        float s = 0.f;
        int iend = min(i0 + 8, NTOP);
        for (int i = i0; i < iend; ++i) s += nw[(size_t)i * NTOP + j];
        atomicAdd(colsum + j, s);
    }
}

// Kernel 2: build B' in MFMA-fragment order:
//   B'[((nt*8 + s)*64 + lane)] (short8) = V_j[n = nt*16 + (lane&15),
//                                             k = s*32 + (lane>>4)*8 + j]
__global__ void k_vj(const float* __restrict__ V,
                     const float* __restrict__ noise,
                     const float* __restrict__ colsum,
                     unsigned short* __restrict__ Bp) {
    int t  = blockIdx.x * 256 + threadIdx.x;   // 0 .. 64*8*64-1 = 32767
    int nt = t >> 9;
    int s  = (t >> 6) & 7;
    int l  = t & 63;
    int lm = l & 15, lq = l >> 4;
    int n  = nt * 16 + lm;
    int k0 = s * 32 + lq * 8;
    union { short8 v; unsigned short us[8]; } pk;
    if (n < NTOP) {
        float cs = colsum[n];
        #pragma unroll
        for (int j = 0; j < 8; ++j) {
            int idx = n * KC + k0 + j;
            pk.us[j] = f2bf(V[idx] * cs + 0.1f * noise[idx]);
        }
    } else {
        #pragma unroll
        for (int j = 0; j < 8; ++j) pk.us[j] = 0;
    }
    reinterpret_cast<short8*>(Bp)[t] = pk.v;
}

// Kernel 3: fused U_emb + GEMM(A@B'^T) + sigmoid + masked Normal log-prob + reduce.
// A-fragments built once per block into LDS. Per ns-iteration: issue ALL 32
// epilogue R/C loads first (32-deep MLP), hide their latency under the MFMA
// phase, then consume from registers. launch_bounds(256,6): no spill (~85 VGPR cap).
__global__ __launch_bounds__(256, 6) void k_main(
    const float* __restrict__ U, const float* __restrict__ w5,
    const float* __restrict__ b1, const short8* __restrict__ Bf,
    const float* __restrict__ R, const int* __restrict__ C,
    float* __restrict__ out)
{
    __shared__ short8 Alds[512];   // 8 s-steps x 64 lanes, 8 KB

    const int tid  = threadIdx.x;
    const int wave = tid >> 6;
    const int l    = tid & 63;
    const int lm = l & 15;       // C/D n within tile
    const int lq = l >> 4;       // quad
    const int m0 = blockIdx.x << 4;

    const float w0 = w5[0], w1 = w5[1], w2 = w5[2], w3 = w5[3], w4 = w5[4];
    const float bb = b1[0];

    // ---- Cooperative A-fragment build: 512 chunks, 2 per thread ----
    // Alds[(s*64 + ll)] (short8) = U_emb[m0 + (ll&15), s*32 + (ll>>4)*8 + j] in bf16
    #pragma unroll
    for (int o = tid; o < 512; o += 256) {
        const int ll = o & 63;
        const int s  = o >> 6;
        const int m  = m0 + (ll & 15);
        const int k0 = (s << 5) + ((ll >> 4) << 3);
        const f32x4* up4 = reinterpret_cast<const f32x4*>(
            U + ((size_t)m * KC + k0) * 5);
        float u[40];
        #pragma unroll
        for (int i = 0; i < 10; ++i) {
            f32x4 t = up4[i];
            u[i*4+0] = t.x; u[i*4+1] = t.y; u[i*4+2] = t.z; u[i*4+3] = t.w;
        }
        union { short8 v; unsigned short us[8]; } pk;
        #pragma unroll
        for (int j = 0; j < 8; ++j) {
            float e = u[j*5+0]*w0 + u[j*5+1]*w1 + u[j*5+2]*w2
                    + u[j*5+3]*w3 + u[j*5+4]*w4 + bb;
            pk.us[j] = f2bf(e);
        }
        Alds[o] = pk.v;
    }
    __syncthreads();

    float lpsum = 0.f;

    for (int ns = wave * 4; ns < wave * 4 + 4; ++ns) {
        const int n0 = ns << 6;

        // ---- Phase 1: issue all 32 R/C loads for this ns (deep MLP) ----
        float rv[16]; int cv[16];
        #pragma unroll
        for (int t = 0; t < 4; ++t) {
            const int n = n0 + t * 16 + lm;
            const size_t base = (size_t)(m0 + (lq << 2)) * NTOP + n;
            if (n < NTOP) {
                #pragma unroll
                for (int r = 0; r < 4; ++r) {
                    rv[t * 4 + r] = R[base + (size_t)r * NTOP];
                    cv[t * 4 + r] = C[base + (size_t)r * NTOP];
                }
            } else {
                #pragma unroll
                for (int r = 0; r < 4; ++r) { rv[t * 4 + r] = 0.f; cv[t * 4 + r] = 0; }
            }
        }

        // ---- Phase 2: MFMA (hides the HBM latency of phase 1) ----
        f32x4 acc[4];
        #pragma unroll
        for (int t = 0; t < 4; ++t) acc[t] = (f32x4){0.f, 0.f, 0.f, 0.f};

        #pragma unroll
        for (int s = 0; s < 8; ++s) {
            const short8 afr = Alds[(s << 6) + l];
            #pragma unroll
            for (int t = 0; t < 4; ++t) {
                const short8 bfr = Bf[(((ns * 4 + t) * 8 + s) << 6) + l];
                acc[t] = __builtin_amdgcn_mfma_f32_16x16x32_bf16(afr, bfr, acc[t], 0, 0, 0);
            }
        }

        // ---- Phase 3: consume from registers ----
        // C/D layout: n = lane&15 (within 16-tile), m = (lane>>4)*4 + reg
        #pragma unroll
        for (int t = 0; t < 4; ++t) {
            #pragma unroll
            for (int r = 0; r < 4; ++r) {
                float x   = acc[t][r];
                float muv = 1.f / (1.f + __expf(-x));
                float d   = rv[t * 4 + r] - muv;
                float lp  = -50.f * d * d + 1.3836465597893728f;
                if (cv[t * 4 + r] == 1) lpsum += lp;
            }
        }
    }

    #pragma unroll
    for (int off = 32; off > 0; off >>= 1) lpsum += __shfl_down(lpsum, off);
    if (l == 0) atomicAdd(out, lpsum);
}

extern "C" void kernel_launch(void* const* d_in, const int* in_sizes, int n_in,
                              void* d_out, int out_size, void* d_ws, size_t ws_size,
                              hipStream_t stream) {
    const float* V     = (const float*)d_in[1];
    const float* R     = (const float*)d_in[2];
    const float* nw    = (const float*)d_in[3];
    const float* U     = (const float*)d_in[4];
    const float* w5    = (const float*)d_in[5];
    const float* b1    = (const float*)d_in[6];
    const float* noise = (const float*)d_in[7];
    const int*   C     = (const int*)d_in[8];
    float* out = (float*)d_out;

    // Workspace (known-safe 532,480 B footprint):
    //   colsum: [0, 4000)      (padded to 8192)
    //   Bp    : [8192, 532480) 1024*256*2 = 524288 B
    float*          colsum = (float*)d_ws;
    unsigned short* Bp     = (unsigned short*)((char*)d_ws + 8192);

    hipMemsetAsync(colsum, 0, NTOP * sizeof(float), stream);
    hipMemsetAsync(out, 0, sizeof(float), stream);
    hipLaunchKernelGGL(k_prep, dim3(4, 125), dim3(256), 0, stream, nw, colsum);
    hipLaunchKernelGGL(k_vj, dim3(128), dim3(256), 0, stream,
                       V, noise, colsum, Bp);
    hipLaunchKernelGGL(k_main, dim3(MROWS / 16), dim3(256), 0, stream,
                       U, w5, b1, (const short8*)Bp, R, C, out);
}

// Round 5
// 254.849 us; speedup vs baseline: 1.4858x; 1.2860x over previous
//
#include <hip/hip_runtime.h>
#include <hip/hip_bf16.h>

typedef __attribute__((ext_vector_type(8))) short short8;
typedef __attribute__((ext_vector_type(4))) float f32x4;

#define NTOP 1000
#define KC   256
#define MROWS 40000

static __device__ __forceinline__ unsigned short f2bf(float x) {
    union { float f; unsigned u; } v; v.f = x;
    unsigned r = (v.u + 0x7FFFu + ((v.u >> 16) & 1u)) >> 16;
    return (unsigned short)r;
}

// Kernel 1: colsum[j] += sum over an 8-row slab of nw. colsum pre-zeroed by memset.
__global__ void k_prep(const float* __restrict__ nw,
                       float* __restrict__ colsum) {
    int j  = blockIdx.x * 256 + threadIdx.x;
    int i0 = blockIdx.y * 8;
    if (j < NTOP) {
        float s = 0.f;
        int iend = min(i0 + 8, NTOP);
        for (int i = i0; i < iend; ++i) s += nw[(size_t)i * NTOP + j];
        atomicAdd(colsum + j, s);
    }
}

// Kernel 2: build B' in MFMA-fragment order:
//   B'[((nt*8 + s)*64 + lane)] (short8) = V_j[n = nt*16 + (lane&15),
//                                             k = s*32 + (lane>>4)*8 + j]
__global__ void k_vj(const float* __restrict__ V,
                     const float* __restrict__ noise,
                     const float* __restrict__ colsum,
                     unsigned short* __restrict__ Bp) {
    int t  = blockIdx.x * 256 + threadIdx.x;   // 0 .. 64*8*64-1 = 32767
    int nt = t >> 9;
    int s  = (t >> 6) & 7;
    int l  = t & 63;
    int lm = l & 15, lq = l >> 4;
    int n  = nt * 16 + lm;
    int k0 = s * 32 + lq * 8;
    union { short8 v; unsigned short us[8]; } pk;
    if (n < NTOP) {
        float cs = colsum[n];
        #pragma unroll
        for (int j = 0; j < 8; ++j) {
            int idx = n * KC + k0 + j;
            pk.us[j] = f2bf(V[idx] * cs + 0.1f * noise[idx]);
        }
    } else {
        #pragma unroll
        for (int j = 0; j < 8; ++j) pk.us[j] = 0;
    }
    reinterpret_cast<short8*>(Bp)[t] = pk.v;
}

// Kernel 3: fused U_emb + GEMM(A@B'^T) + sigmoid + masked Normal log-prob + reduce.
// R/C software-pipelined ONE ITERATION AHEAD in registers. Issue slots are pinned
// with sched_barrier(0) sandwiches so the scheduler cannot sink the loads to their
// uses (round-4 failure: VGPR=40 proved the loads were sunk, MLP ~0.4/wave).
// vmcnt is in-order, so prefetch is issued AFTER the current iteration's Bf loads.
__global__ __launch_bounds__(256, 6) void k_main(
    const float* __restrict__ U, const float* __restrict__ w5,
    const float* __restrict__ b1, const short8* __restrict__ Bf,
    const float* __restrict__ R, const int* __restrict__ C,
    float* __restrict__ out)
{
    __shared__ short8 Alds[512];   // 8 s-steps x 64 lanes, 8 KB

    const int tid  = threadIdx.x;
    const int wave = tid >> 6;
    const int l    = tid & 63;
    const int lm = l & 15;       // C/D n within tile
    const int lq = l >> 4;       // quad
    const int m0 = blockIdx.x << 4;

    const float w0 = w5[0], w1 = w5[1], w2 = w5[2], w3 = w5[3], w4 = w5[4];
    const float bb = b1[0];

    // ---- Cooperative A-fragment build: 512 chunks, 2 per thread ----
    #pragma unroll
    for (int o = tid; o < 512; o += 256) {
        const int ll = o & 63;
        const int s  = o >> 6;
        const int m  = m0 + (ll & 15);
        const int k0 = (s << 5) + ((ll >> 4) << 3);
        const f32x4* up4 = reinterpret_cast<const f32x4*>(
            U + ((size_t)m * KC + k0) * 5);
        float u[40];
        #pragma unroll
        for (int i = 0; i < 10; ++i) {
            f32x4 t = up4[i];
            u[i*4+0] = t.x; u[i*4+1] = t.y; u[i*4+2] = t.z; u[i*4+3] = t.w;
        }
        union { short8 v; unsigned short us[8]; } pk;
        #pragma unroll
        for (int j = 0; j < 8; ++j) {
            float e = u[j*5+0]*w0 + u[j*5+1]*w1 + u[j*5+2]*w2
                    + u[j*5+3]*w3 + u[j*5+4]*w4 + bb;
            pk.us[j] = f2bf(e);
        }
        Alds[o] = pk.v;
    }
    __syncthreads();

    const size_t rbase0 = (size_t)(m0 + (lq << 2)) * NTOP;

    // Load one half (two 16-col tiles) of an ns-iteration's R/C: 16 loads.
    auto LOADH = [&](int ns_, int t0, float* rv_, int* cv_) {
        #pragma unroll
        for (int tt = 0; tt < 2; ++tt) {
            const int n = (ns_ << 6) + (t0 + tt) * 16 + lm;
            const size_t base = rbase0 + n;
            if (n < NTOP) {
                #pragma unroll
                for (int r = 0; r < 4; ++r) {
                    rv_[tt*4+r] = R[base + (size_t)r * NTOP];
                    cv_[tt*4+r] = C[base + (size_t)r * NTOP];
                }
            } else {
                #pragma unroll
                for (int r = 0; r < 4; ++r) { rv_[tt*4+r] = 0.f; cv_[tt*4+r] = 0; }
            }
        }
    };

    // Epilogue half: consume 8 (R, C, acc) triples. Accumulation order identical
    // to previous passing rounds (t ascending, r ascending).
    auto EPI = [&](const f32x4& a0, const f32x4& a1,
                   const float* rv_, const int* cv_, float& sum_) {
        #pragma unroll
        for (int tt = 0; tt < 2; ++tt) {
            #pragma unroll
            for (int r = 0; r < 4; ++r) {
                float x   = tt ? a1[r] : a0[r];
                float muv = 1.f / (1.f + __expf(-x));
                float d   = rv_[tt*4+r] - muv;
                float lp  = -50.f * d * d + 1.3836465597893728f;
                if (cv_[tt*4+r] == 1) sum_ += lp;
            }
        }
    };

    float lpsum = 0.f;
    const int ns0 = wave << 2;

    float rA[8], rB[8]; int cA[8], cB[8];
    LOADH(ns0, 0, rA, cA);     // prologue: first iteration unpipelined
    LOADH(ns0, 2, rB, cB);

    #pragma unroll
    for (int it = 0; it < 4; ++it) {
        const int ns = ns0 + it;

        f32x4 acc[4];
        #pragma unroll
        for (int t = 0; t < 4; ++t) acc[t] = (f32x4){0.f, 0.f, 0.f, 0.f};

        #pragma unroll
        for (int s = 0; s < 8; ++s) {
            const short8 afr = Alds[(s << 6) + l];
            #pragma unroll
            for (int t = 0; t < 4; ++t) {
                const short8 bfr = Bf[(((ns * 4 + t) * 8 + s) << 6) + l];
                acc[t] = __builtin_amdgcn_mfma_f32_16x16x32_bf16(afr, bfr, acc[t], 0, 0, 0);
            }
        }

        float rA2[8], rB2[8]; int cA2[8], cB2[8];

        // ---- pinned issue slot: next-iter half A (after this iter's Bf loads!) ----
        __builtin_amdgcn_sched_barrier(0);
        if (it < 3) LOADH(ns + 1, 0, rA2, cA2);
        __builtin_amdgcn_sched_barrier(0);

        EPI(acc[0], acc[1], rA, cA, lpsum);

        // ---- pinned issue slot: next-iter half B ----
        __builtin_amdgcn_sched_barrier(0);
        if (it < 3) LOADH(ns + 1, 2, rB2, cB2);
        __builtin_amdgcn_sched_barrier(0);

        EPI(acc[2], acc[3], rB, cB, lpsum);

        if (it < 3) {
            #pragma unroll
            for (int k = 0; k < 8; ++k) {
                rA[k] = rA2[k]; cA[k] = cA2[k];
                rB[k] = rB2[k]; cB[k] = cB2[k];
            }
        }
    }

    #pragma unroll
    for (int off = 32; off > 0; off >>= 1) lpsum += __shfl_down(lpsum, off);
    if (l == 0) atomicAdd(out, lpsum);
}

extern "C" void kernel_launch(void* const* d_in, const int* in_sizes, int n_in,
                              void* d_out, int out_size, void* d_ws, size_t ws_size,
                              hipStream_t stream) {
    const float* V     = (const float*)d_in[1];
    const float* R     = (const float*)d_in[2];
    const float* nw    = (const float*)d_in[3];
    const float* U     = (const float*)d_in[4];
    const float* w5    = (const float*)d_in[5];
    const float* b1    = (const float*)d_in[6];
    const float* noise = (const float*)d_in[7];
    const int*   C     = (const int*)d_in[8];
    float* out = (float*)d_out;

    // Workspace (known-safe 532,480 B footprint):
    //   colsum: [0, 4000)      (padded to 8192)
    //   Bp    : [8192, 532480) 1024*256*2 = 524288 B
    float*          colsum = (float*)d_ws;
    unsigned short* Bp     = (unsigned short*)((char*)d_ws + 8192);

    hipMemsetAsync(colsum, 0, NTOP * sizeof(float), stream);
    hipMemsetAsync(out, 0, sizeof(float), stream);
    hipLaunchKernelGGL(k_prep, dim3(4, 125), dim3(256), 0, stream, nw, colsum);
    hipLaunchKernelGGL(k_vj, dim3(128), dim3(256), 0, stream,
                       V, noise, colsum, Bp);
    hipLaunchKernelGGL(k_main, dim3(MROWS / 16), dim3(256), 0, stream,
                       U, w5, b1, (const short8*)Bp, R, C, out);
}